// Round 1
// baseline (432.178 us; speedup 1.0000x reference)
//
#include <hip/hip_runtime.h>
#include <math.h>

// Problem constants (fixed by setup_inputs): B=4, L=S=2048, H=8, E=D=64.
#define BDIM 4
#define LDIM 2048
#define HDIM 8
#define EDIM 64
#define TQ 64
#define TK 64
#define LDP 68   // LDS leading-dim pad: 16B-aligned float4 rows, conflict-free reads

__global__ __launch_bounds__(256, 3)
void fa_causal_fp32(const float* __restrict__ Q, const float* __restrict__ K,
                    const float* __restrict__ V, float* __restrict__ O) {
    // sQT[e][r]: Q tile transposed, pre-scaled by 1/sqrt(E)
    // sKT[e][c]: K tile transposed
    // sV [c][d]: V tile natural layout
    __shared__ float sQT[EDIM][LDP];
    __shared__ float sKT[EDIM][LDP];
    __shared__ float sV [TK][LDP];

    const int t  = threadIdx.x;
    const int bh = blockIdx.x;            // 0..31
    const int b  = bh >> 3;
    const int h  = bh & 7;
    const int qt = (int)(gridDim.y - 1) - (int)blockIdx.y;  // heavy tiles first
    const int q0 = qt * TQ;

    const int tr = t >> 4;                // 0..15 (row group)
    const int tc = t & 15;                // 0..15 (col/d group)
    const int r0 = tr << 2;               // 4 rows
    const int c0 = tc << 2;               // 4 cols == 4 d's

    // ---- stage Q (scaled, transposed), once ----
    {
        const int sr = t >> 2;            // 0..63
        const int se = (t & 3) << 4;      // 0,16,32,48
        const float* qrow = Q + (size_t)(((b * LDIM + q0 + sr) * HDIM + h)) * EDIM;
        #pragma unroll
        for (int w = 0; w < 4; ++w) {
            const float4 v4 = *(const float4*)(qrow + se + 4 * w);
            sQT[se + 4 * w + 0][sr] = v4.x * 0.125f;
            sQT[se + 4 * w + 1][sr] = v4.y * 0.125f;
            sQT[se + 4 * w + 2][sr] = v4.z * 0.125f;
            sQT[se + 4 * w + 3][sr] = v4.w * 0.125f;
        }
    }

    float m_i[4], l_i[4], acc[4][4];
    #pragma unroll
    for (int i = 0; i < 4; ++i) {
        m_i[i] = -INFINITY;
        l_i[i] = 0.0f;
        #pragma unroll
        for (int j = 0; j < 4; ++j) acc[i][j] = 0.0f;
    }

    for (int kt = 0; kt <= qt; ++kt) {
        const int k0 = kt * TK;

        // ---- stage K (transposed) + V ----
        {
            const int sr = t >> 2;
            const int se = (t & 3) << 4;
            const float* krow = K + (size_t)(((b * LDIM + k0 + sr) * HDIM + h)) * EDIM;
            const float* vrow = V + (size_t)(((b * LDIM + k0 + sr) * HDIM + h)) * EDIM;
            #pragma unroll
            for (int w = 0; w < 4; ++w) {
                const float4 kv = *(const float4*)(krow + se + 4 * w);
                sKT[se + 4 * w + 0][sr] = kv.x;
                sKT[se + 4 * w + 1][sr] = kv.y;
                sKT[se + 4 * w + 2][sr] = kv.z;
                sKT[se + 4 * w + 3][sr] = kv.w;
                *(float4*)(&sV[sr][se + 4 * w]) = *(const float4*)(vrow + se + 4 * w);
            }
        }
        __syncthreads();

        // ---- scores: s[i][j] = scale * Q[r0+i] . K[c0+j] ----
        float sv[4][4];
        #pragma unroll
        for (int i = 0; i < 4; ++i)
            #pragma unroll
            for (int j = 0; j < 4; ++j) sv[i][j] = 0.0f;

        #pragma unroll 8
        for (int e = 0; e < EDIM; ++e) {
            const float4 qv = *(const float4*)&sQT[e][r0];
            const float4 kv = *(const float4*)&sKT[e][c0];
            sv[0][0] += qv.x * kv.x; sv[0][1] += qv.x * kv.y;
            sv[0][2] += qv.x * kv.z; sv[0][3] += qv.x * kv.w;
            sv[1][0] += qv.y * kv.x; sv[1][1] += qv.y * kv.y;
            sv[1][2] += qv.y * kv.z; sv[1][3] += qv.y * kv.w;
            sv[2][0] += qv.z * kv.x; sv[2][1] += qv.z * kv.y;
            sv[2][2] += qv.z * kv.z; sv[2][3] += qv.z * kv.w;
            sv[3][0] += qv.w * kv.x; sv[3][1] += qv.w * kv.y;
            sv[3][2] += qv.w * kv.z; sv[3][3] += qv.w * kv.w;
        }

        // ---- causal mask: only the diagonal tile needs it ----
        if (kt == qt) {
            #pragma unroll
            for (int i = 0; i < 4; ++i)
                #pragma unroll
                for (int j = 0; j < 4; ++j)
                    if (c0 + j > r0 + i) sv[i][j] = -INFINITY;
        }

        // ---- online softmax (row stats across the 16-lane row group) ----
        #pragma unroll
        for (int i = 0; i < 4; ++i) {
            float rm = fmaxf(fmaxf(sv[i][0], sv[i][1]), fmaxf(sv[i][2], sv[i][3]));
            rm = fmaxf(rm, __shfl_xor(rm, 1));
            rm = fmaxf(rm, __shfl_xor(rm, 2));
            rm = fmaxf(rm, __shfl_xor(rm, 4));
            rm = fmaxf(rm, __shfl_xor(rm, 8));
            const float mn = fmaxf(m_i[i], rm);        // finite: every row has >=1 valid col
            const float alpha = __expf(m_i[i] - mn);   // 0 on first tile (m=-inf)
            m_i[i] = mn;
            float rs = 0.0f;
            #pragma unroll
            for (int j = 0; j < 4; ++j) {
                const float p = __expf(sv[i][j] - mn); // masked -> exp(-inf)=0
                sv[i][j] = p;
                rs += p;
            }
            rs += __shfl_xor(rs, 1);
            rs += __shfl_xor(rs, 2);
            rs += __shfl_xor(rs, 4);
            rs += __shfl_xor(rs, 8);
            l_i[i] = l_i[i] * alpha + rs;
            #pragma unroll
            for (int j = 0; j < 4; ++j) acc[i][j] *= alpha;
        }

        // ---- P·V: broadcast P across the row group via shfl, V from LDS ----
        #pragma unroll 2
        for (int cc = 0; cc < 16; ++cc) {
            #pragma unroll
            for (int jj = 0; jj < 4; ++jj) {
                const int c = (cc << 2) | jj;
                const float4 vv = *(const float4*)&sV[c][c0];
                const float p0 = __shfl(sv[0][jj], cc, 16);
                const float p1 = __shfl(sv[1][jj], cc, 16);
                const float p2 = __shfl(sv[2][jj], cc, 16);
                const float p3 = __shfl(sv[3][jj], cc, 16);
                acc[0][0] += p0 * vv.x; acc[0][1] += p0 * vv.y;
                acc[0][2] += p0 * vv.z; acc[0][3] += p0 * vv.w;
                acc[1][0] += p1 * vv.x; acc[1][1] += p1 * vv.y;
                acc[1][2] += p1 * vv.z; acc[1][3] += p1 * vv.w;
                acc[2][0] += p2 * vv.x; acc[2][1] += p2 * vv.y;
                acc[2][2] += p2 * vv.z; acc[2][3] += p2 * vv.w;
                acc[3][0] += p3 * vv.x; acc[3][1] += p3 * vv.y;
                acc[3][2] += p3 * vv.z; acc[3][3] += p3 * vv.w;
            }
        }

        __syncthreads();   // protect sKT/sV before next tile's staging
    }

    // ---- epilogue: O[b, q0+r0+i, h, c0..c0+3] = acc[i][:] / l[i] ----
    #pragma unroll
    for (int i = 0; i < 4; ++i) {
        const float inv = 1.0f / l_i[i];
        float4 o;
        o.x = acc[i][0] * inv; o.y = acc[i][1] * inv;
        o.z = acc[i][2] * inv; o.w = acc[i][3] * inv;
        float* orow = O + (size_t)(((b * LDIM + q0 + r0 + i) * HDIM + h)) * EDIM;
        *(float4*)(orow + c0) = o;
    }
}

extern "C" void kernel_launch(void* const* d_in, const int* in_sizes, int n_in,
                              void* d_out, int out_size, void* d_ws, size_t ws_size,
                              hipStream_t stream) {
    const float* Q = (const float*)d_in[0];
    const float* K = (const float*)d_in[1];
    const float* V = (const float*)d_in[2];
    float* O = (float*)d_out;
    dim3 grid(BDIM * HDIM, LDIM / TQ);   // (32 bh, 32 q-tiles)
    fa_causal_fp32<<<grid, 256, 0, stream>>>(Q, K, V, O);
}

// Round 2
// 202.756 us; speedup vs baseline: 2.1315x; 2.1315x over previous
//
#include <hip/hip_runtime.h>
#include <math.h>

// B=4, L=S=2048, H=8, E=D=64 (fixed by setup_inputs)
#define BD 4
#define LD 2048
#define HD 8
#define ED 64
#define TQ 64
#define TK 64

typedef __attribute__((ext_vector_type(8))) short bf16x8;   // 8 bf16 = 4 VGPR (MFMA A/B frag)
typedef __attribute__((ext_vector_type(4))) float f32x4;    // MFMA C/D frag

// fp32 -> bf16 round-to-nearest-even (inputs are finite normals)
__device__ inline short f2bf(float f) {
    unsigned int u = __builtin_bit_cast(unsigned int, f);
    u += 0x7fffu + ((u >> 16) & 1u);
    return (short)(u >> 16);
}

// Swizzled LDS byte address: 64 bf16 per row (128B), 16B groups XOR'd by row&7.
// All frag reads / staged writes land <=2-way on banks (2-way is free, m136).
__device__ inline int swz(int row, int bcol) {
    return row * 128 + ((((bcol >> 4) ^ row) & 7) << 4) + (bcol & 15);
}

__global__ __launch_bounds__(256, 4)
void fa_mfma_bf16(const float* __restrict__ Q, const float* __restrict__ K,
                  const float* __restrict__ V, float* __restrict__ O) {
    // sK : K-tile [s][e]   64x64 bf16, swizzled rows      (8 KB)
    // sVT: V-tile [d][s]   64x64 bf16 transposed, swizzled (8 KB)
    // sP : per-wave P tile [m][s] 16x64 bf16, swizzled     (4 x 2 KB)
    __shared__ __align__(16) char smem[24576];
    char* sK  = smem;
    char* sVT = smem + 8192;

    const int t    = threadIdx.x;
    const int lane = t & 63;
    const int w    = t >> 6;            // wave 0..3
    const int m16  = lane & 15;
    const int quad = lane >> 4;         // 0..3

    const int bh = blockIdx.x;          // 0..31
    const int b  = bh >> 3;
    const int h  = bh & 7;
    const int qt = (int)(gridDim.y - 1) - (int)blockIdx.y;   // heavy tiles first
    const int q0 = qt * TQ;

    char* sP = smem + 16384 + w * 2048;

    // ---- Q fragments, loaded once. scale*log2(e) folded in so softmax uses exp2.
    const float qscale = 0.125f * 1.44269504088896340736f;
    bf16x8 qf[2];
    {
        const float* qrow = Q + (size_t)((b * LD + q0 + w * 16 + m16) * HD + h) * ED;
        #pragma unroll
        for (int ks = 0; ks < 2; ++ks) {
            const float4 x = *(const float4*)(qrow + ks * 32 + quad * 8);
            const float4 y = *(const float4*)(qrow + ks * 32 + quad * 8 + 4);
            bf16x8 f;
            f[0] = f2bf(x.x * qscale); f[1] = f2bf(x.y * qscale);
            f[2] = f2bf(x.z * qscale); f[3] = f2bf(x.w * qscale);
            f[4] = f2bf(y.x * qscale); f[5] = f2bf(y.y * qscale);
            f[6] = f2bf(y.z * qscale); f[7] = f2bf(y.w * qscale);
            qf[ks] = f;
        }
    }

    f32x4 oacc[4];
    float m_i[4], l_i[4];
    #pragma unroll
    for (int i = 0; i < 4; ++i) {
        m_i[i] = -INFINITY; l_i[i] = 0.0f;
        oacc[i] = (f32x4){0.f, 0.f, 0.f, 0.f};
    }

    for (int kt = 0; kt <= qt; ++kt) {
        const int k0 = kt * TK;

        // ---- stage K [s][e] and V transposed [d][s], fp32 -> bf16
        {
            const int s  = t >> 2;           // 0..63
            const int cb = (t & 3) * 4;      // 0,4,8,12
            const float* krow = K + (size_t)((b * LD + k0 + s) * HD + h) * ED;
            const float* vrow = V + (size_t)((b * LD + k0 + s) * HD + h) * ED;
            #pragma unroll
            for (int ww = 0; ww < 4; ++ww) {
                const int c = cb + 16 * ww;  // e (for K) / d (for V), 4-wide
                const float4 kx = *(const float4*)(krow + c);
                const unsigned long long pk =
                      ((unsigned long long)(unsigned short)f2bf(kx.x))
                    | ((unsigned long long)(unsigned short)f2bf(kx.y) << 16)
                    | ((unsigned long long)(unsigned short)f2bf(kx.z) << 32)
                    | ((unsigned long long)(unsigned short)f2bf(kx.w) << 48);
                *(unsigned long long*)(sK + swz(s, 2 * c)) = pk;
                const float4 vx = *(const float4*)(vrow + c);
                *(short*)(sVT + swz(c + 0, 2 * s)) = f2bf(vx.x);
                *(short*)(sVT + swz(c + 1, 2 * s)) = f2bf(vx.y);
                *(short*)(sVT + swz(c + 2, 2 * s)) = f2bf(vx.z);
                *(short*)(sVT + swz(c + 3, 2 * s)) = f2bf(vx.w);
            }
        }
        __syncthreads();

        // ---- S = Q K^T  (C layout: row = quad*4+i, col = k0 + nt*16 + m16)
        f32x4 sacc[4];
        #pragma unroll
        for (int nt = 0; nt < 4; ++nt) {
            const bf16x8 kf0 = *(const bf16x8*)(sK + swz(nt * 16 + m16, quad * 16));
            const bf16x8 kf1 = *(const bf16x8*)(sK + swz(nt * 16 + m16, 64 + quad * 16));
            f32x4 z = {0.f, 0.f, 0.f, 0.f};
            z = __builtin_amdgcn_mfma_f32_16x16x32_bf16(qf[0], kf0, z, 0, 0, 0);
            z = __builtin_amdgcn_mfma_f32_16x16x32_bf16(qf[1], kf1, z, 0, 0, 0);
            sacc[nt] = z;
        }

        // ---- causal mask: only the diagonal k-tile
        if (kt == qt) {
            #pragma unroll
            for (int nt = 0; nt < 4; ++nt)
                #pragma unroll
                for (int i = 0; i < 4; ++i)
                    if (nt * 16 + m16 > w * 16 + quad * 4 + i)   // k0 == q0 here
                        sacc[nt][i] = -INFINITY;
        }

        // ---- online softmax (row r = quad*4+i; reduce across the 16-lane group)
        float alpha[4];
        #pragma unroll
        for (int i = 0; i < 4; ++i) {
            float mx = fmaxf(fmaxf(sacc[0][i], sacc[1][i]),
                             fmaxf(sacc[2][i], sacc[3][i]));
            mx = fmaxf(mx, __shfl_xor(mx, 1));
            mx = fmaxf(mx, __shfl_xor(mx, 2));
            mx = fmaxf(mx, __shfl_xor(mx, 4));
            mx = fmaxf(mx, __shfl_xor(mx, 8));
            const float mn = fmaxf(m_i[i], mx);
            alpha[i] = __builtin_amdgcn_exp2f(m_i[i] - mn);  // 0 on first tile
            m_i[i] = mn;
            float rs = 0.0f;
            #pragma unroll
            for (int nt = 0; nt < 4; ++nt) {
                const float p = __builtin_amdgcn_exp2f(sacc[nt][i] - mn); // masked -> 0
                sacc[nt][i] = p;
                rs += p;
            }
            rs += __shfl_xor(rs, 1);
            rs += __shfl_xor(rs, 2);
            rs += __shfl_xor(rs, 4);
            rs += __shfl_xor(rs, 8);
            l_i[i] = l_i[i] * alpha[i] + rs;
        }
        #pragma unroll
        for (int nt = 0; nt < 4; ++nt)
            #pragma unroll
            for (int i = 0; i < 4; ++i)
                oacc[nt][i] *= alpha[i];

        // ---- P: C layout -> LDS [m][s] (per-wave buffer; DS is in-order per wave)
        #pragma unroll
        for (int nt = 0; nt < 4; ++nt)
            #pragma unroll
            for (int i = 0; i < 4; ++i)
                *(short*)(sP + swz(quad * 4 + i, 2 * (nt * 16 + m16))) = f2bf(sacc[nt][i]);

        // ---- O += P V  (A = P from LDS in A-layout; B = V^T rows, contiguous)
        const bf16x8 pa0 = *(const bf16x8*)(sP + swz(m16, quad * 16));
        const bf16x8 pa1 = *(const bf16x8*)(sP + swz(m16, 64 + quad * 16));
        #pragma unroll
        for (int nt = 0; nt < 4; ++nt) {
            const bf16x8 vf0 = *(const bf16x8*)(sVT + swz(nt * 16 + m16, quad * 16));
            const bf16x8 vf1 = *(const bf16x8*)(sVT + swz(nt * 16 + m16, 64 + quad * 16));
            oacc[nt] = __builtin_amdgcn_mfma_f32_16x16x32_bf16(pa0, vf0, oacc[nt], 0, 0, 0);
            oacc[nt] = __builtin_amdgcn_mfma_f32_16x16x32_bf16(pa1, vf1, oacc[nt], 0, 0, 0);
        }

        __syncthreads();   // protect sK/sVT before next tile's staging
    }

    // ---- epilogue: O[b, q0+w*16+quad*4+i, h, nt*16+m16] = oacc/l
    #pragma unroll
    for (int i = 0; i < 4; ++i) {
        const float inv = 1.0f / l_i[i];
        float* orow = O + (size_t)((b * LD + q0 + w * 16 + quad * 4 + i) * HD + h) * ED;
        #pragma unroll
        for (int nt = 0; nt < 4; ++nt)
            orow[nt * 16 + m16] = oacc[nt][i] * inv;
    }
}

extern "C" void kernel_launch(void* const* d_in, const int* in_sizes, int n_in,
                              void* d_out, int out_size, void* d_ws, size_t ws_size,
                              hipStream_t stream) {
    const float* Q = (const float*)d_in[0];
    const float* K = (const float*)d_in[1];
    const float* V = (const float*)d_in[2];
    float* O = (float*)d_out;
    dim3 grid(BD * HD, LD / TQ);   // 32 x 32 = 1024 blocks
    fa_mfma_bf16<<<grid, 256, 0, stream>>>(Q, K, V, O);
}